// Round 1
// baseline (98.783 us; speedup 1.0000x reference)
//
#include <hip/hip_runtime.h>

#define UNITS 256
#define IN_DIM 16
#define CH 2
#define R0C 64
#define R1C 8
#define R2C 2
#define NROWS 262144

#define NBLK 1024
#define ROWS_PER_BLOCK (NROWS / NBLK)   // 256
#define CHUNK 64

__device__ __forceinline__ float fast_tanh_scaled(float a, float g) {
    // tanh(a) * g = g - 2*g*rcp(1+exp(2a))
    float e = __expf(2.0f * a);
    float r = __builtin_amdgcn_rcpf(1.0f + e);
    return __builtin_fmaf(-2.0f * g, r, g);
}

// Build w[u][j][c] = sum_n (sum_a f0[u,a] * core[a,j,n]) * f2[c,n]
__global__ void wprep_kernel(const float* __restrict__ core,
                             const float* __restrict__ f0,
                             const float* __restrict__ f2,
                             float* __restrict__ w) {
    int u = threadIdx.x;  // 256 threads, 1 block
    float r0[R1C][R2C] = {};
    #pragma unroll 8
    for (int a = 0; a < R0C; ++a) {
        float f0v = f0[u * R0C + a];
        #pragma unroll
        for (int j = 0; j < R1C; ++j)
            #pragma unroll
            for (int n = 0; n < R2C; ++n)
                r0[j][n] += f0v * core[(a * R1C + j) * R2C + n];
    }
    #pragma unroll
    for (int j = 0; j < R1C; ++j)
        #pragma unroll
        for (int c = 0; c < CH; ++c)
            w[(u * R1C + j) * CH + c] =
                r0[j][0] * f2[c * R2C + 0] + r0[j][1] * f2[c * R2C + 1];
}

template <bool INLINE_W>
__global__ __launch_bounds__(256) void mdense_main(
    const float* __restrict__ x,     // [N][16]
    const float* __restrict__ f1,    // [16][8]
    const float* __restrict__ bias,  // [256][2]
    const float* __restrict__ fac,   // [256][2]
    const float* __restrict__ wg,    // [256][8][2] (ws) — used if !INLINE_W
    const float* __restrict__ core,  // used if INLINE_W
    const float* __restrict__ f0,    // used if INLINE_W
    const float* __restrict__ f2,    // used if INLINE_W
    float* __restrict__ out)         // [N][256]
{
    __shared__ float Xs[CHUNK * IN_DIM];  // 4 KB
    __shared__ float Ys[CHUNK * R1C];     // 2 KB
    __shared__ float F1s[IN_DIM * R1C];   // 512 B

    const int tid = threadIdx.x;
    const int u = tid;

    // per-unit weights w[j][c]
    float w[R1C][CH];
    if (INLINE_W) {
        float r0[R1C][R2C] = {};
        #pragma unroll 8
        for (int a = 0; a < R0C; ++a) {
            float f0v = f0[u * R0C + a];
            #pragma unroll
            for (int j = 0; j < R1C; ++j)
                #pragma unroll
                for (int n = 0; n < R2C; ++n)
                    r0[j][n] += f0v * core[(a * R1C + j) * R2C + n];
        }
        #pragma unroll
        for (int j = 0; j < R1C; ++j)
            #pragma unroll
            for (int c = 0; c < CH; ++c)
                w[j][c] = r0[j][0] * f2[c * R2C + 0] + r0[j][1] * f2[c * R2C + 1];
    } else {
        #pragma unroll
        for (int j = 0; j < R1C; ++j) {
            float2 t = *reinterpret_cast<const float2*>(&wg[(u * R1C + j) * CH]);
            w[j][0] = t.x;
            w[j][1] = t.y;
        }
    }
    const float b0 = bias[u * CH + 0], b1 = bias[u * CH + 1];
    const float g0 = fac[u * CH + 0], g1 = fac[u * CH + 1];

    if (tid < 32) {
        reinterpret_cast<float4*>(F1s)[tid] =
            reinterpret_cast<const float4*>(f1)[tid];
    }

    const long rowbase = (long)blockIdx.x * ROWS_PER_BLOCK;
    for (int c = 0; c < ROWS_PER_BLOCK / CHUNK; ++c) {
        const long base = rowbase + (long)c * CHUNK;
        __syncthreads();  // Ys/Xs from prev chunk fully consumed; F1s visible
        // stage X: 64 rows x 16 floats, one float4 per thread, coalesced
        reinterpret_cast<float4*>(Xs)[tid] =
            reinterpret_cast<const float4*>(x + base * IN_DIM)[tid];
        __syncthreads();
        // Y[r][j] = sum_i X[r][i] * f1[i][j]; thread -> (r = tid>>2, 2 j's)
        {
            const int r = tid >> 2, j0 = (tid & 3) * 2;
            float y0 = 0.f, y1 = 0.f;
            #pragma unroll
            for (int i = 0; i < IN_DIM; ++i) {
                float xi = Xs[r * IN_DIM + i];
                y0 = __builtin_fmaf(xi, F1s[i * R1C + j0], y0);
                y1 = __builtin_fmaf(xi, F1s[i * R1C + j0 + 1], y1);
            }
            Ys[r * R1C + j0] = y0;
            Ys[r * R1C + j0 + 1] = y1;
        }
        __syncthreads();
        // main loop: one output element per thread per row
        #pragma unroll 4
        for (int r = 0; r < CHUNK; ++r) {
            const float4 ya = reinterpret_cast<const float4*>(&Ys[r * R1C])[0];
            const float4 yb = reinterpret_cast<const float4*>(&Ys[r * R1C])[1];
            float a0 = b0, a1 = b1;
            a0 = __builtin_fmaf(ya.x, w[0][0], a0);
            a1 = __builtin_fmaf(ya.x, w[0][1], a1);
            a0 = __builtin_fmaf(ya.y, w[1][0], a0);
            a1 = __builtin_fmaf(ya.y, w[1][1], a1);
            a0 = __builtin_fmaf(ya.z, w[2][0], a0);
            a1 = __builtin_fmaf(ya.z, w[2][1], a1);
            a0 = __builtin_fmaf(ya.w, w[3][0], a0);
            a1 = __builtin_fmaf(ya.w, w[3][1], a1);
            a0 = __builtin_fmaf(yb.x, w[4][0], a0);
            a1 = __builtin_fmaf(yb.x, w[4][1], a1);
            a0 = __builtin_fmaf(yb.y, w[5][0], a0);
            a1 = __builtin_fmaf(yb.y, w[5][1], a1);
            a0 = __builtin_fmaf(yb.z, w[6][0], a0);
            a1 = __builtin_fmaf(yb.z, w[6][1], a1);
            a0 = __builtin_fmaf(yb.w, w[7][0], a0);
            a1 = __builtin_fmaf(yb.w, w[7][1], a1);
            float o = fast_tanh_scaled(a0, g0) + fast_tanh_scaled(a1, g1);
            out[(base + r) * UNITS + u] = o;
        }
    }
}

extern "C" void kernel_launch(void* const* d_in, const int* in_sizes, int n_in,
                              void* d_out, int out_size, void* d_ws, size_t ws_size,
                              hipStream_t stream) {
    const float* x    = (const float*)d_in[0];
    const float* core = (const float*)d_in[1];
    const float* f0   = (const float*)d_in[2];
    const float* f1   = (const float*)d_in[3];
    const float* f2   = (const float*)d_in[4];
    const float* bias = (const float*)d_in[5];
    const float* fac  = (const float*)d_in[6];
    float* out = (float*)d_out;

    const size_t wbytes = UNITS * R1C * CH * sizeof(float);  // 16 KB
    if (ws_size >= wbytes) {
        float* w = (float*)d_ws;
        wprep_kernel<<<1, 256, 0, stream>>>(core, f0, f2, w);
        mdense_main<false><<<NBLK, 256, 0, stream>>>(x, f1, bias, fac, w,
                                                     core, f0, f2, out);
    } else {
        mdense_main<true><<<NBLK, 256, 0, stream>>>(x, f1, bias, fac, nullptr,
                                                    core, f0, f2, out);
    }
}

// Round 2
// 94.006 us; speedup vs baseline: 1.0508x; 1.0508x over previous
//
#include <hip/hip_runtime.h>

#define UNITS 256
#define IN_DIM 16
#define CH 2
#define R0C 64
#define R1C 8
#define R2C 2
#define NROWS 262144

#define NBLK 1024                      // 4096 waves; each wave: 2 chunks of 64 rows
#define NCHUNK (NROWS / 64)            // 4096
#define K2LOG2E 2.8853900817779268f    // 2*log2(e)

typedef float v2f __attribute__((ext_vector_type(2)));

// ws layout (floats): wl[256][8][2] @0 (scaled by 2log2e), aux[256]{bl0,bl1,m0,m1} @4096,
// gs[256] @5120. Total 5376 floats = 21504 bytes.
#define WS_FLOATS 5376

__global__ void wprep_kernel(const float* __restrict__ core,
                             const float* __restrict__ f0,
                             const float* __restrict__ f2,
                             const float* __restrict__ bias,
                             const float* __restrict__ fac,
                             float* __restrict__ ws) {
    int u = threadIdx.x;  // 256 threads, 1 block
    float r0[R1C][R2C] = {};
    #pragma unroll 8
    for (int a = 0; a < R0C; ++a) {
        float f0v = f0[u * R0C + a];
        #pragma unroll
        for (int j = 0; j < R1C; ++j)
            #pragma unroll
            for (int n = 0; n < R2C; ++n)
                r0[j][n] += f0v * core[(a * R1C + j) * R2C + n];
    }
    #pragma unroll
    for (int j = 0; j < R1C; ++j) {
        float w0 = r0[j][0] * f2[0 * R2C + 0] + r0[j][1] * f2[0 * R2C + 1];
        float w1 = r0[j][0] * f2[1 * R2C + 0] + r0[j][1] * f2[1 * R2C + 1];
        ws[(u * R1C + j) * CH + 0] = w0 * K2LOG2E;
        ws[(u * R1C + j) * CH + 1] = w1 * K2LOG2E;
    }
    float fc0 = fac[u * CH + 0], fc1 = fac[u * CH + 1];
    float4 aux;
    aux.x = bias[u * CH + 0] * K2LOG2E;
    aux.y = bias[u * CH + 1] * K2LOG2E;
    aux.z = -2.0f * fc0;
    aux.w = -2.0f * fc1;
    reinterpret_cast<float4*>(ws + 4096)[u] = aux;
    ws[5120 + u] = fc0 + fc1;
}

__device__ __forceinline__ void unit_params(int u, const float* core,
                                            const float* f0, const float* f2,
                                            const float* bias, const float* fac,
                                            v2f wv[R1C], float& bl0, float& bl1,
                                            float& m0, float& m1, float& gs) {
    float r0[R1C][R2C] = {};
    #pragma unroll 8
    for (int a = 0; a < R0C; ++a) {
        float f0v = f0[u * R0C + a];
        #pragma unroll
        for (int j = 0; j < R1C; ++j)
            #pragma unroll
            for (int n = 0; n < R2C; ++n)
                r0[j][n] += f0v * core[(a * R1C + j) * R2C + n];
    }
    #pragma unroll
    for (int j = 0; j < R1C; ++j) {
        float w0 = r0[j][0] * f2[0] + r0[j][1] * f2[1];
        float w1 = r0[j][0] * f2[2] + r0[j][1] * f2[3];
        wv[j] = (v2f){w0 * K2LOG2E, w1 * K2LOG2E};
    }
    float fc0 = fac[u * CH + 0], fc1 = fac[u * CH + 1];
    bl0 = bias[u * CH + 0] * K2LOG2E;
    bl1 = bias[u * CH + 1] * K2LOG2E;
    m0 = -2.0f * fc0;
    m1 = -2.0f * fc1;
    gs = fc0 + fc1;
}

template <bool USE_WS>
__global__ __launch_bounds__(256) void mdense_main(
    const float* __restrict__ x,      // [N][16]
    const float* __restrict__ f1,     // [16][8]
    const float* __restrict__ wsbuf,  // prepped params (USE_WS)
    const float* __restrict__ core, const float* __restrict__ f0,
    const float* __restrict__ f2, const float* __restrict__ bias,
    const float* __restrict__ fac,
    float* __restrict__ out)          // [N][256]
{
    __shared__ float F1s[IN_DIM * R1C];  // 512 B
    const int tid = threadIdx.x;
    if (tid < 32)
        reinterpret_cast<float4*>(F1s)[tid] = reinterpret_cast<const float4*>(f1)[tid];
    __syncthreads();  // only block-wide sync in the kernel

    const int W = blockIdx.x * 4 + (tid >> 6);  // global wave id, 0..4095
    const int lane = tid & 63;
    const int half = W & 1;
    const int cbase = W >> 1;           // 0..2047
    const int u0 = half * 128 + lane * 2;

    // per-lane unit parameters (2 units)
    v2f wv0[R1C], wv1[R1C];
    float bl00, bl01, m00, m01, gs0;
    float bl10, bl11, m10, m11, gs1;
    if (USE_WS) {
        const v2f* wlv = reinterpret_cast<const v2f*>(wsbuf);
        #pragma unroll
        for (int j = 0; j < R1C; ++j) {
            wv0[j] = wlv[u0 * R1C + j];
            wv1[j] = wlv[(u0 + 1) * R1C + j];
        }
        float4 a0 = reinterpret_cast<const float4*>(wsbuf + 4096)[u0];
        float4 a1 = reinterpret_cast<const float4*>(wsbuf + 4096)[u0 + 1];
        bl00 = a0.x; bl01 = a0.y; m00 = a0.z; m01 = a0.w;
        bl10 = a1.x; bl11 = a1.y; m10 = a1.z; m11 = a1.w;
        gs0 = wsbuf[5120 + u0];
        gs1 = wsbuf[5120 + u0 + 1];
    } else {
        unit_params(u0, core, f0, f2, bias, fac, wv0, bl00, bl01, m00, m01, gs0);
        unit_params(u0 + 1, core, f0, f2, bias, fac, wv1, bl10, bl11, m10, m11, gs1);
    }

    #pragma unroll
    for (int cc = 0; cc < 2; ++cc) {
        const int chunk = cbase + cc * 2048;
        const size_t rowbase = (size_t)chunk * 64;

        // lane r loads its own x-row into registers
        const float4* xp = reinterpret_cast<const float4*>(x + (rowbase + lane) * IN_DIM);
        float4 X0 = xp[0], X1 = xp[1], X2 = xp[2], X3 = xp[3];
        float xs[16] = {X0.x, X0.y, X0.z, X0.w, X1.x, X1.y, X1.z, X1.w,
                        X2.x, X2.y, X2.z, X2.w, X3.x, X3.y, X3.z, X3.w};

        // Y[lane-row][0..7] = x-row . f1, fully in registers
        v2f Yv[4] = {(v2f){0.f, 0.f}, (v2f){0.f, 0.f}, (v2f){0.f, 0.f}, (v2f){0.f, 0.f}};
        #pragma unroll
        for (int i = 0; i < IN_DIM; ++i) {
            float xi = xs[i];
            v2f xv = {xi, xi};
            float4 ha = *reinterpret_cast<const float4*>(&F1s[i * R1C]);
            float4 hb = *reinterpret_cast<const float4*>(&F1s[i * R1C + 4]);
            Yv[0] += xv * (v2f){ha.x, ha.y};
            Yv[1] += xv * (v2f){ha.z, ha.w};
            Yv[2] += xv * (v2f){hb.x, hb.y};
            Yv[3] += xv * (v2f){hb.z, hb.w};
        }
        float yl[8] = {Yv[0][0], Yv[0][1], Yv[1][0], Yv[1][1],
                       Yv[2][0], Yv[2][1], Yv[3][0], Yv[3][1]};

        float* orow = out + rowbase * UNITS + u0;
        #pragma unroll 4
        for (int r = 0; r < 64; ++r) {
            // broadcast row r's Y via readlane (ALU, no LDS)
            float yr[8];
            #pragma unroll
            for (int j = 0; j < R1C; ++j)
                yr[j] = __int_as_float(
                    __builtin_amdgcn_readlane(__float_as_int(yl[j]), r));

            v2f a0 = {bl00, bl01};
            v2f a1 = {bl10, bl11};
            #pragma unroll
            for (int j = 0; j < R1C; ++j) {
                v2f ys = {yr[j], yr[j]};
                a0 += ys * wv0[j];
                a1 += ys * wv1[j];
            }
            // tanh(z)*g summed over channels:
            // e = exp2(a) (a already includes 2*log2e scale); t*g = g - 2g*rcp(1+e)
            float e00 = __builtin_amdgcn_exp2f(a0[0]);
            float e01 = __builtin_amdgcn_exp2f(a0[1]);
            float e10 = __builtin_amdgcn_exp2f(a1[0]);
            float e11 = __builtin_amdgcn_exp2f(a1[1]);
            float r00 = __builtin_amdgcn_rcpf(1.0f + e00);
            float r01 = __builtin_amdgcn_rcpf(1.0f + e01);
            float r10 = __builtin_amdgcn_rcpf(1.0f + e10);
            float r11 = __builtin_amdgcn_rcpf(1.0f + e11);
            float o0 = __builtin_fmaf(m00, r00, __builtin_fmaf(m01, r01, gs0));
            float o1 = __builtin_fmaf(m10, r10, __builtin_fmaf(m11, r11, gs1));
            *reinterpret_cast<float2*>(orow) = make_float2(o0, o1);
            orow += UNITS;
        }
    }
}

extern "C" void kernel_launch(void* const* d_in, const int* in_sizes, int n_in,
                              void* d_out, int out_size, void* d_ws, size_t ws_size,
                              hipStream_t stream) {
    const float* x    = (const float*)d_in[0];
    const float* core = (const float*)d_in[1];
    const float* f0   = (const float*)d_in[2];
    const float* f1   = (const float*)d_in[3];
    const float* f2   = (const float*)d_in[4];
    const float* bias = (const float*)d_in[5];
    const float* fac  = (const float*)d_in[6];
    float* out = (float*)d_out;

    if (ws_size >= WS_FLOATS * sizeof(float)) {
        float* ws = (float*)d_ws;
        wprep_kernel<<<1, 256, 0, stream>>>(core, f0, f2, bias, fac, ws);
        mdense_main<true><<<NBLK, 256, 0, stream>>>(x, f1, ws, core, f0, f2,
                                                    bias, fac, out);
    } else {
        mdense_main<false><<<NBLK, 256, 0, stream>>>(x, f1, nullptr, core, f0,
                                                     f2, bias, fac, out);
    }
}

// Round 4
// 67.491 us; speedup vs baseline: 1.4636x; 1.3929x over previous
//
#include <hip/hip_runtime.h>

#define UNITS 256
#define IN_DIM 16
#define CH 2
#define R0C 64
#define R1C 8
#define R2C 2
#define NROWS 262144

#define NBLK 1024                    // 4096 waves, one 64-row chunk each
#define K2LOG2E 2.8853900817779268f  // 2*log2(e)

typedef float v2f __attribute__((ext_vector_type(2)));
typedef float v4f __attribute__((ext_vector_type(4)));

// ws: per-unit 24 floats: w[8][2]*2log2e (16), bl0,bl1 (*2log2e), m0,m1, gs, pad3
#define UPACK 24
#define WS_FLOATS (UNITS * UPACK)

__device__ __forceinline__ void compute_unit_params(
    int u, const float* __restrict__ core, const float* __restrict__ f0,
    const float* __restrict__ f2, const float* __restrict__ bias,
    const float* __restrict__ fac, float wout[16], float aux[5]) {
    float r0[R1C][R2C] = {};
    #pragma unroll 8
    for (int a = 0; a < R0C; ++a) {
        float f0v = f0[u * R0C + a];
        #pragma unroll
        for (int j = 0; j < R1C; ++j)
            #pragma unroll
            for (int n = 0; n < R2C; ++n)
                r0[j][n] += f0v * core[(a * R1C + j) * R2C + n];
    }
    #pragma unroll
    for (int j = 0; j < R1C; ++j) {
        float w0 = r0[j][0] * f2[0 * R2C + 0] + r0[j][1] * f2[0 * R2C + 1];
        float w1 = r0[j][0] * f2[1 * R2C + 0] + r0[j][1] * f2[1 * R2C + 1];
        wout[j * 2 + 0] = w0 * K2LOG2E;
        wout[j * 2 + 1] = w1 * K2LOG2E;
    }
    float fc0 = fac[u * CH + 0], fc1 = fac[u * CH + 1];
    aux[0] = bias[u * CH + 0] * K2LOG2E;
    aux[1] = bias[u * CH + 1] * K2LOG2E;
    aux[2] = -2.0f * fc0;
    aux[3] = -2.0f * fc1;
    aux[4] = fc0 + fc1;
}

__global__ void wprep_kernel(const float* __restrict__ core,
                             const float* __restrict__ f0,
                             const float* __restrict__ f2,
                             const float* __restrict__ bias,
                             const float* __restrict__ fac,
                             float* __restrict__ ws) {
    int u = threadIdx.x;  // 256 threads, 1 block
    float w[16], aux[5];
    compute_unit_params(u, core, f0, f2, bias, fac, w, aux);
    float* p = ws + u * UPACK;
    #pragma unroll
    for (int k = 0; k < 16; ++k) p[k] = w[k];
    #pragma unroll
    for (int k = 0; k < 5; ++k) p[16 + k] = aux[k];
    p[21] = 0.f; p[22] = 0.f; p[23] = 0.f;
}

template <bool USE_WS>
__global__ __launch_bounds__(256) void mdense_main(
    const float* __restrict__ x,      // [N][16]
    const float* __restrict__ f1,     // [16][8]
    const float* __restrict__ wsbuf,  // packed params (USE_WS)
    const float* __restrict__ core, const float* __restrict__ f0,
    const float* __restrict__ f2, const float* __restrict__ bias,
    const float* __restrict__ fac,
    float* __restrict__ out)          // [N][256]
{
    __shared__ float F1s[IN_DIM * R1C];  // 512 B
    const int tid = threadIdx.x;
    if (tid < 32)
        reinterpret_cast<float4*>(F1s)[tid] = reinterpret_cast<const float4*>(f1)[tid];
    __syncthreads();

    const int W = blockIdx.x * 4 + (tid >> 6);  // chunk id, 0..4095
    const int lane = tid & 63;
    const int u0 = lane * 4;  // this lane's 4 consecutive units

    // ---- per-lane params for 4 units ----
    v2f wv[4][R1C];     // weights (pre-scaled)
    v2f blv[4], mv[4];  // bias*2log2e, -2*fac
    float gs[4];        // fac0+fac1
    if (USE_WS) {
        #pragma unroll
        for (int q = 0; q < 4; ++q) {
            const float4* p4 = reinterpret_cast<const float4*>(wsbuf + (u0 + q) * UPACK);
            float4 w0 = p4[0], w1 = p4[1], w2 = p4[2], w3 = p4[3], a = p4[4];
            wv[q][0] = (v2f){w0.x, w0.y}; wv[q][1] = (v2f){w0.z, w0.w};
            wv[q][2] = (v2f){w1.x, w1.y}; wv[q][3] = (v2f){w1.z, w1.w};
            wv[q][4] = (v2f){w2.x, w2.y}; wv[q][5] = (v2f){w2.z, w2.w};
            wv[q][6] = (v2f){w3.x, w3.y}; wv[q][7] = (v2f){w3.z, w3.w};
            blv[q] = (v2f){a.x, a.y};
            mv[q]  = (v2f){a.z, a.w};
            gs[q] = wsbuf[(u0 + q) * UPACK + 20];
        }
    } else {
        for (int q = 0; q < 4; ++q) {
            float w[16], aux[5];
            compute_unit_params(u0 + q, core, f0, f2, bias, fac, w, aux);
            #pragma unroll
            for (int j = 0; j < R1C; ++j) wv[q][j] = (v2f){w[j * 2], w[j * 2 + 1]};
            blv[q] = (v2f){aux[0], aux[1]};
            mv[q]  = (v2f){aux[2], aux[3]};
            gs[q] = aux[4];
        }
    }

    // ---- load this lane's x row, compute its Y[8] ----
    const size_t rowbase = (size_t)W * 64;
    const float4* xp = reinterpret_cast<const float4*>(x + (rowbase + lane) * IN_DIM);
    float4 X0 = xp[0], X1 = xp[1], X2 = xp[2], X3 = xp[3];
    const float xs[16] = {X0.x, X0.y, X0.z, X0.w, X1.x, X1.y, X1.z, X1.w,
                          X2.x, X2.y, X2.z, X2.w, X3.x, X3.y, X3.z, X3.w};
    v2f Yv[4] = {(v2f){0.f, 0.f}, (v2f){0.f, 0.f}, (v2f){0.f, 0.f}, (v2f){0.f, 0.f}};
    #pragma unroll
    for (int i = 0; i < IN_DIM; ++i) {
        v2f xv = {xs[i], xs[i]};
        float4 ha = *reinterpret_cast<const float4*>(&F1s[i * R1C]);
        float4 hb = *reinterpret_cast<const float4*>(&F1s[i * R1C + 4]);
        Yv[0] += xv * (v2f){ha.x, ha.y};
        Yv[1] += xv * (v2f){ha.z, ha.w};
        Yv[2] += xv * (v2f){hb.x, hb.y};
        Yv[3] += xv * (v2f){hb.z, hb.w};
    }
    float yl[8] = {Yv[0][0], Yv[0][1], Yv[1][0], Yv[1][1],
                   Yv[2][0], Yv[2][1], Yv[3][0], Yv[3][1]};

    // ---- 64 rows: broadcast Y via readlane, 4 units/lane, float4 nt store ----
    float* obase = out + rowbase * UNITS;
    #pragma unroll 2
    for (int r = 0; r < 64; ++r) {
        float yr[8];
        #pragma unroll
        for (int j = 0; j < R1C; ++j)
            yr[j] = __int_as_float(
                __builtin_amdgcn_readlane(__float_as_int(yl[j]), r));

        v2f acc0 = blv[0], acc1 = blv[1], acc2 = blv[2], acc3 = blv[3];
        #pragma unroll
        for (int j = 0; j < R1C; ++j) {
            v2f ys = {yr[j], yr[j]};
            acc0 += ys * wv[0][j];
            acc1 += ys * wv[1][j];
            acc2 += ys * wv[2][j];
            acc3 += ys * wv[3][j];
        }
        v4f o;
        {
            float e0 = __builtin_amdgcn_exp2f(acc0[0]);
            float e1 = __builtin_amdgcn_exp2f(acc0[1]);
            float r0 = __builtin_amdgcn_rcpf(1.0f + e0);
            float r1 = __builtin_amdgcn_rcpf(1.0f + e1);
            o.x = __builtin_fmaf(mv[0][0], r0, __builtin_fmaf(mv[0][1], r1, gs[0]));
        }
        {
            float e0 = __builtin_amdgcn_exp2f(acc1[0]);
            float e1 = __builtin_amdgcn_exp2f(acc1[1]);
            float r0 = __builtin_amdgcn_rcpf(1.0f + e0);
            float r1 = __builtin_amdgcn_rcpf(1.0f + e1);
            o.y = __builtin_fmaf(mv[1][0], r0, __builtin_fmaf(mv[1][1], r1, gs[1]));
        }
        {
            float e0 = __builtin_amdgcn_exp2f(acc2[0]);
            float e1 = __builtin_amdgcn_exp2f(acc2[1]);
            float r0 = __builtin_amdgcn_rcpf(1.0f + e0);
            float r1 = __builtin_amdgcn_rcpf(1.0f + e1);
            o.z = __builtin_fmaf(mv[2][0], r0, __builtin_fmaf(mv[2][1], r1, gs[2]));
        }
        {
            float e0 = __builtin_amdgcn_exp2f(acc3[0]);
            float e1 = __builtin_amdgcn_exp2f(acc3[1]);
            float r0 = __builtin_amdgcn_rcpf(1.0f + e0);
            float r1 = __builtin_amdgcn_rcpf(1.0f + e1);
            o.w = __builtin_fmaf(mv[3][0], r0, __builtin_fmaf(mv[3][1], r1, gs[3]));
        }
        v4f* p4 = reinterpret_cast<v4f*>(obase + (size_t)r * UNITS) + lane;
        __builtin_nontemporal_store(o, p4);
    }
}

extern "C" void kernel_launch(void* const* d_in, const int* in_sizes, int n_in,
                              void* d_out, int out_size, void* d_ws, size_t ws_size,
                              hipStream_t stream) {
    const float* x    = (const float*)d_in[0];
    const float* core = (const float*)d_in[1];
    const float* f0   = (const float*)d_in[2];
    const float* f1   = (const float*)d_in[3];
    const float* f2   = (const float*)d_in[4];
    const float* bias = (const float*)d_in[5];
    const float* fac  = (const float*)d_in[6];
    float* out = (float*)d_out;

    if (ws_size >= WS_FLOATS * sizeof(float)) {
        float* ws = (float*)d_ws;
        wprep_kernel<<<1, 256, 0, stream>>>(core, f0, f2, bias, fac, ws);
        mdense_main<true><<<NBLK, 256, 0, stream>>>(x, f1, ws, core, f0, f2,
                                                    bias, fac, out);
    } else {
        mdense_main<false><<<NBLK, 256, 0, stream>>>(x, f1, nullptr, core, f0,
                                                     f2, bias, fac, out);
    }
}